// Round 9
// baseline (116.798 us; speedup 1.0000x reference)
//
#include <hip/hip_runtime.h>
#include <hip/hip_fp16.h>

namespace {
constexpr int A_N = 96;
constexpr int U_N = 128;
constexpr int V_N = 128;
constexpr int W_N = 128;
constexpr int H_N = 128;
constexpr int NSTEPS = 128;
constexpr float T_HALF = 89.80256121069154f;
constexpr float DT = 1.4031650189170554f;   // 2*T/NSTEPS
constexpr float INV_DT = 1.0f / DT;
constexpr int RAYS_PER_BLOCK = 8;           // 128-thread blocks
constexpr int BLOCK_THREADS = RAYS_PER_BLOCK * 16;
constexpr int SEGS = 4;
constexpr int SEG_STEPS = NSTEPS / SEGS;    // 32
constexpr size_t VOL_ELEMS = (size_t)W_N * H_N * V_N;             // 2M
constexpr size_t VOLH_BYTES = VOL_ELEMS * sizeof(unsigned short); // 4 MB
constexpr size_t SINO = (size_t)U_N * A_N * V_N;                  // 1.57M floats
constexpr int TAB_STRIDE = SEG_STEPS + 1;   // 33: LDS bank-conflict padding
}

// ---- bit-cast helpers (no __half2_as_uint in HIP) ----
__device__ __forceinline__ unsigned int h2u(__half2 h) {
    union { __half2 h; unsigned int u; } v; v.h = h; return v.u;
}
__device__ __forceinline__ __half2 u2h(unsigned int u) {
    union { unsigned int u; __half2 h; } v; v.u = u; return v.h;
}

// ---- pre-pass: fp32 volume -> f16 (rte), 8 values/thread ----
__device__ __forceinline__ unsigned int packh2(float a, float b) {
    return (unsigned int)__half_as_ushort(__float2half_rn(a)) |
           ((unsigned int)__half_as_ushort(__float2half_rn(b)) << 16);
}

__global__ __launch_bounds__(256) void vol_to_f16(
    const float* __restrict__ vol, unsigned int* __restrict__ volh)
{
    const size_t i = (size_t)blockIdx.x * 256 + threadIdx.x;
    const float4 f0 = *(const float4*)(vol + 8 * i);
    const float4 f1 = *(const float4*)(vol + 8 * i + 4);
    uint4 o;
    o.x = packh2(f0.x, f0.y);
    o.y = packh2(f0.z, f0.w);
    o.z = packh2(f1.x, f1.y);
    o.w = packh2(f1.z, f1.w);
    *(uint4*)(volh + 4 * i) = o;
}

// ---- main projector: LDS geometry table + f16 volume + SW-pipelined loop ----
__global__ __launch_bounds__(BLOCK_THREADS) void joseph_fwd_tab(
    const unsigned short* __restrict__ volh,
    const float* __restrict__ angles,
    float* __restrict__ dst, float scale)
{
    __shared__ uint4 s_offs[RAYS_PER_BLOCK * TAB_STRIDE];  // 4 column byte-offsets
    __shared__ uint4 s_wts [RAYS_PER_BLOCK * TAB_STRIDE];  // 4 dup'd half2 weights

    const int a  = blockIdx.y;
    const int i0 = blockIdx.z * SEG_STEPS;

    const float ang = angles[a];
    const float cv = cosf(ang);
    const float sv = sinf(ang);

    // ---- build the 8-ray x 32-step geometry table ----
    for (int e = threadIdx.x; e < RAYS_PER_BLOCK * SEG_STEPS; e += BLOCK_THREADS) {
        const int r = e >> 5;           // ray in block
        const int k = e & 31;           // step in segment
        const float up = (float)(blockIdx.x * RAYS_PER_BLOCK + r) - 63.5f;
        const float xb = fmaf(-up, sv, 63.5f);
        const float yb = fmaf( up, cv, 63.5f);
        const float t  = fmaf((float)(i0 + k) + 0.5f, DT, -T_HALF);
        const float xi = fmaf(t, cv, xb);
        const float yi = fmaf(t, sv, yb);

        const float fx0f = floorf(xi);
        const float fy0f = floorf(yi);
        const int x0 = (int)fx0f;
        const int y0 = (int)fy0f;
        const float fx = xi - fx0f;
        const float fy = yi - fy0f;
        const int x1 = x0 + 1;
        const int y1 = y0 + 1;

        const float wx0 = (x0 >= 0 && x0 < W_N) ? (1.f - fx) : 0.f;
        const float wx1 = (x1 >= 0 && x1 < W_N) ? fx : 0.f;
        const float wy0 = (y0 >= 0 && y0 < H_N) ? (1.f - fy) : 0.f;
        const float wy1 = (y1 >= 0 && y1 < H_N) ? fy : 0.f;

        const int cx0 = min(max(x0, 0), W_N - 1);
        const int cx1 = min(max(x1, 0), W_N - 1);
        const int cy0 = min(max(y0, 0), H_N - 1);
        const int cy1 = min(max(y1, 0), H_N - 1);

        uint4 off;                      // f16 column = 128*2 = 256 B
        off.x = (unsigned)(((cx0 << 7) + cy0) << 8);
        off.y = (unsigned)(((cx1 << 7) + cy0) << 8);
        off.z = (unsigned)(((cx0 << 7) + cy1) << 8);
        off.w = (unsigned)(((cx1 << 7) + cy1) << 8);

        uint4 w;
        w.x = h2u(__float2half2_rn(wx0 * wy0));
        w.y = h2u(__float2half2_rn(wx1 * wy0));
        w.z = h2u(__float2half2_rn(wx0 * wy1));
        w.w = h2u(__float2half2_rn(wx1 * wy1));

        const int idx = r * TAB_STRIDE + k;
        s_offs[idx] = off;
        s_wts[idx]  = w;
    }
    __syncthreads();

    // ---- per-thread ray setup ----
    const int zo  = threadIdx.x & 15;
    const int r   = threadIdx.x >> 4;
    const int u_i = blockIdx.x * RAYS_PER_BLOCK + r;
    const unsigned lane16 = (unsigned)(zo << 4);
    const char* __restrict__ volc = (const char*)volh;

    const float up = (float)u_i - 63.5f;
    const float xb = fmaf(-up, sv, 63.5f);
    const float yb = fmaf( up, cv, 63.5f);

    // valid-step range within this segment
    const int i1 = i0 + SEG_STEPS;
    float tlo = -2.f * T_HALF, thi = 2.f * T_HALF;
    if (fabsf(cv) > 1e-6f) {
        const float ta = (-1.f - xb) / cv, tb = (128.f - xb) / cv;
        tlo = fmaxf(tlo, fminf(ta, tb));
        thi = fminf(thi, fmaxf(ta, tb));
    } else if (xb <= -1.f || xb >= 128.f) { thi = tlo - 1.f; }
    if (fabsf(sv) > 1e-6f) {
        const float ta = (-1.f - yb) / sv, tb = (128.f - yb) / sv;
        tlo = fmaxf(tlo, fminf(ta, tb));
        thi = fminf(thi, fmaxf(ta, tb));
    } else if (yb <= -1.f || yb >= 128.f) { thi = tlo - 1.f; }
    const int ilo = (int)floorf(fmaf(tlo + T_HALF, INV_DT, -0.5f)) - 1;
    const int ihi = (int)ceilf (fmaf(thi + T_HALF, INV_DT, -0.5f)) + 1;
    int lo = min(max(ilo, i0), i1);
    int hi = min(max(ihi + 1, i0), i1);
    if (hi < lo) hi = lo;
    const int lo8 = (lo - i0) & ~7;            // segment-local, 8-aligned
    const int hi8 = (hi - i0 + 7) & ~7;

    float accf[8];
#pragma unroll
    for (int k = 0; k < 8; ++k) accf[k] = 0.f;

    const __half2 hz = __float2half2_rn(0.f);
    const int ebase = r * TAB_STRIDE;
    const int n8 = hi8 - lo8;                  // multiple of 8 (may be 0)

    if (n8 > 0) {
        // prologue: load step lo8
        uint4 wcur = s_wts[ebase + lo8];
        {
            const uint4 off = s_offs[ebase + lo8];
        }
        uint4 offc = s_offs[ebase + lo8];
        uint4 q00 = *(const uint4*)(volc + (offc.x + lane16));
        uint4 q01 = *(const uint4*)(volc + (offc.y + lane16));
        uint4 q10 = *(const uint4*)(volc + (offc.z + lane16));
        uint4 q11 = *(const uint4*)(volc + (offc.w + lane16));

        for (int c = 0; c < n8; c += 8) {
            __half2 a0 = hz, a1 = hz, a2 = hz, a3 = hz;
#pragma unroll
            for (int k = 0; k < 8; ++k) {
                // prefetch step (c+k+1); wrap to lo8 on the last step (harmless)
                const int nk = c + k + 1;
                const int pf = ebase + lo8 + ((nk < n8) ? nk : 0);
                const uint4 offn = s_offs[pf];
                const uint4 wn   = s_wts [pf];
                const uint4 p00 = *(const uint4*)(volc + (offn.x + lane16));
                const uint4 p01 = *(const uint4*)(volc + (offn.y + lane16));
                const uint4 p10 = *(const uint4*)(volc + (offn.z + lane16));
                const uint4 p11 = *(const uint4*)(volc + (offn.w + lane16));

                // consume current step
                const __half2 w00 = u2h(wcur.x);
                const __half2 w01 = u2h(wcur.y);
                const __half2 w10 = u2h(wcur.z);
                const __half2 w11 = u2h(wcur.w);
                const __half2* h00 = (const __half2*)&q00;
                const __half2* h01 = (const __half2*)&q01;
                const __half2* h10 = (const __half2*)&q10;
                const __half2* h11 = (const __half2*)&q11;

                a0 = __hfma2(w00, h00[0], __hfma2(w01, h01[0], __hfma2(w10, h10[0], __hfma2(w11, h11[0], a0))));
                a1 = __hfma2(w00, h00[1], __hfma2(w01, h01[1], __hfma2(w10, h10[1], __hfma2(w11, h11[1], a1))));
                a2 = __hfma2(w00, h00[2], __hfma2(w01, h01[2], __hfma2(w10, h10[2], __hfma2(w11, h11[2], a2))));
                a3 = __hfma2(w00, h00[3], __hfma2(w01, h01[3], __hfma2(w10, h10[3], __hfma2(w11, h11[3], a3))));

                // rotate pipeline registers
                q00 = p00; q01 = p01; q10 = p10; q11 = p11; wcur = wn;
            }
            accf[0] += __low2float(a0); accf[1] += __high2float(a0);
            accf[2] += __low2float(a1); accf[3] += __high2float(a1);
            accf[4] += __low2float(a2); accf[5] += __high2float(a2);
            accf[6] += __low2float(a3); accf[7] += __high2float(a3);
        }
    }

    float* op = dst + (size_t)blockIdx.z * SINO + ((size_t)u_i * A_N + a) * V_N + 8 * zo;
    *(float4*)(op)     = make_float4(accf[0] * scale, accf[1] * scale, accf[2] * scale, accf[3] * scale);
    *(float4*)(op + 4) = make_float4(accf[4] * scale, accf[5] * scale, accf[6] * scale, accf[7] * scale);
}

// ---- reduce: out = (p0+p1+p2+p3) * DT ----
__global__ __launch_bounds__(256) void reduce_segs(
    const float4* __restrict__ p, float4* __restrict__ out)
{
    const size_t i = (size_t)blockIdx.x * 256 + threadIdx.x;
    const size_t q = SINO / 4;
    const float4 a = p[i];
    const float4 b = p[i + q];
    const float4 c = p[i + 2 * q];
    const float4 d = p[i + 3 * q];
    out[i] = make_float4((a.x + b.x + c.x + d.x) * DT,
                         (a.y + b.y + c.y + d.y) * DT,
                         (a.z + b.z + c.z + d.z) * DT,
                         (a.w + b.w + c.w + d.w) * DT);
}

// ---- fallback: fp32 volume, no workspace needed ----
__global__ __launch_bounds__(256) void joseph_fwd_f32(
    const float* __restrict__ vol,
    const float* __restrict__ angles,
    float* __restrict__ out)
{
    const int zo  = threadIdx.x & 15;
    const int r   = threadIdx.x >> 4;
    const int u_i = blockIdx.x * 16 + r;
    const int a   = blockIdx.y;

    const float ang = angles[a];
    const float c = cosf(ang);
    const float s = sinf(ang);
    const float u = (float)u_i - 63.5f;
    const float xb = fmaf(-u, s, 63.5f);
    const float yb = fmaf( u, c, 63.5f);

    const float* volz = vol + 8 * zo;
    float4 accA = make_float4(0.f, 0.f, 0.f, 0.f);
    float4 accB = make_float4(0.f, 0.f, 0.f, 0.f);

    for (int i = 0; i < NSTEPS; ++i) {
        const float t  = fmaf((float)i + 0.5f, DT, -T_HALF);
        const float xi = fmaf(t, c, xb);
        const float yi = fmaf(t, s, yb);
        const float fx0f = floorf(xi);
        const float fy0f = floorf(yi);
        const int x0 = (int)fx0f;
        const int y0 = (int)fy0f;
        const float fx = xi - fx0f;
        const float fy = yi - fy0f;
        const int x1 = x0 + 1;
        const int y1 = y0 + 1;
        const float wx0 = (x0 >= 0 && x0 < W_N) ? (1.f - fx) : 0.f;
        const float wx1 = (x1 >= 0 && x1 < W_N) ? fx : 0.f;
        const float wy0 = (y0 >= 0 && y0 < H_N) ? (1.f - fy) : 0.f;
        const float wy1 = (y1 >= 0 && y1 < H_N) ? fy : 0.f;
        if ((wx0 + wx1) == 0.f || (wy0 + wy1) == 0.f) continue;
        const int cx0 = min(max(x0, 0), W_N - 1);
        const int cx1 = min(max(x1, 0), W_N - 1);
        const int cy0 = min(max(y0, 0), H_N - 1);
        const int cy1 = min(max(y1, 0), H_N - 1);
        const float* p00 = volz + ((cx0 * H_N + cy0) << 7);
        const float* p01 = volz + ((cx1 * H_N + cy0) << 7);
        const float* p10 = volz + ((cx0 * H_N + cy1) << 7);
        const float* p11 = volz + ((cx1 * H_N + cy1) << 7);
        const float4 v00a = *(const float4*)(p00);
        const float4 v00b = *(const float4*)(p00 + 4);
        const float4 v01a = *(const float4*)(p01);
        const float4 v01b = *(const float4*)(p01 + 4);
        const float4 v10a = *(const float4*)(p10);
        const float4 v10b = *(const float4*)(p10 + 4);
        const float4 v11a = *(const float4*)(p11);
        const float4 v11b = *(const float4*)(p11 + 4);
        const float w00 = wx0 * wy0, w01 = wx1 * wy0, w10 = wx0 * wy1, w11 = wx1 * wy1;
        accA.x = fmaf(w00, v00a.x, fmaf(w01, v01a.x, fmaf(w10, v10a.x, fmaf(w11, v11a.x, accA.x))));
        accA.y = fmaf(w00, v00a.y, fmaf(w01, v01a.y, fmaf(w10, v10a.y, fmaf(w11, v11a.y, accA.y))));
        accA.z = fmaf(w00, v00a.z, fmaf(w01, v01a.z, fmaf(w10, v10a.z, fmaf(w11, v11a.z, accA.z))));
        accA.w = fmaf(w00, v00a.w, fmaf(w01, v01a.w, fmaf(w10, v10a.w, fmaf(w11, v11a.w, accA.w))));
        accB.x = fmaf(w00, v00b.x, fmaf(w01, v01b.x, fmaf(w10, v10b.x, fmaf(w11, v11b.x, accB.x))));
        accB.y = fmaf(w00, v00b.y, fmaf(w01, v01b.y, fmaf(w10, v10b.y, fmaf(w11, v11b.y, accB.y))));
        accB.z = fmaf(w00, v00b.z, fmaf(w01, v01b.z, fmaf(w10, v10b.z, fmaf(w11, v11b.z, accB.z))));
        accB.w = fmaf(w00, v00b.w, fmaf(w01, v01b.w, fmaf(w10, v10b.w, fmaf(w11, v11b.w, accB.w))));
    }

    float* op = out + ((size_t)u_i * A_N + a) * V_N + 8 * zo;
    *(float4*)(op)     = make_float4(accA.x * DT, accA.y * DT, accA.z * DT, accA.w * DT);
    *(float4*)(op + 4) = make_float4(accB.x * DT, accB.y * DT, accB.z * DT, accB.w * DT);
}

extern "C" void kernel_launch(void* const* d_in, const int* in_sizes, int n_in,
                              void* d_out, int out_size, void* d_ws, size_t ws_size,
                              hipStream_t stream) {
    const float* vol    = (const float*)d_in[0];
    const float* angles = (const float*)d_in[1];
    float* out          = (float*)d_out;

    const size_t need_full = VOLH_BYTES + SEGS * SINO * sizeof(float);

    if (ws_size >= VOLH_BYTES) {
        unsigned int* volh = (unsigned int*)d_ws;
        hipLaunchKernelGGL(vol_to_f16, dim3(VOL_ELEMS / 8 / 256), dim3(256), 0, stream,
                           vol, volh);
        if (ws_size >= need_full) {
            float* partial = (float*)((char*)d_ws + VOLH_BYTES);
            dim3 grid(U_N / RAYS_PER_BLOCK, A_N, SEGS);
            hipLaunchKernelGGL(joseph_fwd_tab, grid, dim3(BLOCK_THREADS), 0, stream,
                               (const unsigned short*)volh, angles, partial, 1.0f);
            hipLaunchKernelGGL(reduce_segs, dim3(SINO / 4 / 256), dim3(256), 0, stream,
                               (const float4*)partial, (float4*)out);
        } else {
            dim3 grid(U_N / RAYS_PER_BLOCK, A_N, 1);
            hipLaunchKernelGGL(joseph_fwd_tab, grid, dim3(BLOCK_THREADS), 0, stream,
                               (const unsigned short*)volh, angles, out, DT);
        }
    } else {
        dim3 grid(U_N / 16, A_N);
        hipLaunchKernelGGL(joseph_fwd_f32, grid, dim3(256), 0, stream, vol, angles, out);
    }
}

// Round 11
// 115.874 us; speedup vs baseline: 1.0080x; 1.0080x over previous
//
#include <hip/hip_runtime.h>
#include <hip/hip_fp16.h>

namespace {
constexpr int A_N = 96;
constexpr int U_N = 128;
constexpr int V_N = 128;
constexpr int W_N = 128;
constexpr int H_N = 128;
constexpr int NSTEPS = 128;
constexpr float T_HALF = 89.80256121069154f;
constexpr float DT = 1.4031650189170554f;   // 2*T/NSTEPS
constexpr float INV_DT = 1.0f / DT;
constexpr int PAD = 4;                      // zero border: kills all bounds checks
constexpr int WP = W_N + 2 * PAD;           // 136 padded columns per row
constexpr int ROW_BYTES = WP * 256;         // x-stride in bytes (f16 column=256B)
constexpr int RAYS_PER_BLOCK = 8;           // 128-thread blocks
constexpr int BLOCK_THREADS = RAYS_PER_BLOCK * 16;
constexpr int SEGS = 2;
constexpr size_t VOLP_COLS = (size_t)WP * WP;          // 18496 columns
constexpr size_t VOLP_BYTES = VOLP_COLS * 256;         // ~4.73 MB
constexpr size_t SINO = (size_t)U_N * A_N * V_N;       // 1.57M floats
}

// ---- pack two floats -> half2 bits ----
__device__ __forceinline__ unsigned int packh2(float a, float b) {
    return (unsigned int)__half_as_ushort(__float2half_rn(a)) |
           ((unsigned int)__half_as_ushort(__float2half_rn(b)) << 16);
}

// ---- pre-pass: fp32 volume -> padded f16 volume (zero border of PAD cols) ----
__global__ __launch_bounds__(256) void vol_pad_f16(
    const float* __restrict__ vol, unsigned int* __restrict__ volp)
{
    const int idx = blockIdx.x * 256 + threadIdx.x;    // WP*WP*16 threads
    if (idx >= (int)(VOLP_COLS * 16)) return;
    const int zo  = idx & 15;
    const int col = idx >> 4;
    const int yp = col % WP;
    const int xp = col / WP;
    const int x = xp - PAD;
    const int y = yp - PAD;
    uint4 o = make_uint4(0u, 0u, 0u, 0u);
    if ((unsigned)x < 128u && (unsigned)y < 128u) {
        const float* src = vol + (((size_t)x * 128 + y) << 7) + zo * 8;
        const float4 f0 = *(const float4*)(src);
        const float4 f1 = *(const float4*)(src + 4);
        o.x = packh2(f0.x, f0.y);
        o.y = packh2(f0.z, f0.w);
        o.z = packh2(f1.x, f1.y);
        o.w = packh2(f1.z, f1.w);
    }
    *(uint4*)((char*)volp + (size_t)col * 256 + zo * 16) = o;
}

// ---- main projector: barrier-free, inline geometry, padded f16 volume ----
__global__ __launch_bounds__(BLOCK_THREADS) void joseph_fwd_inc(
    const unsigned short* __restrict__ volp,
    const float* __restrict__ angles,
    float* __restrict__ dst, float scale)
{
    const int zo  = threadIdx.x & 15;        // 16 z-groups of 8
    const int r   = threadIdx.x >> 4;        // ray in block
    const int u_i = blockIdx.x * RAYS_PER_BLOCK + r;
    const int a   = blockIdx.y;

    const int spseg = NSTEPS / gridDim.z;
    const int i0 = blockIdx.z * spseg;
    const int i1 = i0 + spseg;

    const float ang = angles[a];
    const float cv = cosf(ang);
    const float sv = sinf(ang);
    const float up = (float)u_i - 63.5f;
    const float xb = fmaf(-up, sv, 63.5f);
    const float yb = fmaf( up, cv, 63.5f);

    // valid-step range: xi,yi in (-1,128); +-2-step slop stays inside PAD=4
    float tlo = -2.f * T_HALF, thi = 2.f * T_HALF;
    if (fabsf(cv) > 1e-6f) {
        const float ta = (-1.f - xb) / cv, tb = (128.f - xb) / cv;
        tlo = fmaxf(tlo, fminf(ta, tb));
        thi = fminf(thi, fmaxf(ta, tb));
    } else if (xb <= -1.f || xb >= 128.f) { thi = tlo - 1.f; }
    if (fabsf(sv) > 1e-6f) {
        const float ta = (-1.f - yb) / sv, tb = (128.f - yb) / sv;
        tlo = fmaxf(tlo, fminf(ta, tb));
        thi = fminf(thi, fmaxf(ta, tb));
    } else if (yb <= -1.f || yb >= 128.f) { thi = tlo - 1.f; }
    const int ilo = (int)floorf(fmaf(tlo + T_HALF, INV_DT, -0.5f)) - 1;
    const int ihi = (int)ceilf (fmaf(thi + T_HALF, INV_DT, -0.5f)) + 1;
    const int lo = min(max(ilo, i0), i1);
    const int hi = min(max(ihi + 1, i0), i1);

    const char* __restrict__ volc = (const char*)volp;
    const int lane16 = zo << 4;

    float accf[8];
#pragma unroll
    for (int k = 0; k < 8; ++k) accf[k] = 0.f;

    for (int i = lo; i < hi; ++i) {
        const float tf = fmaf((float)i + 0.5f, DT, -T_HALF);
        const float xi = fmaf(tf, cv, xb);
        const float yi = fmaf(tf, sv, yb);
        const float fx0 = floorf(xi);
        const float fy0 = floorf(yi);
        const float fx = xi - fx0;
        const float fy = yi - fy0;
        const int x0 = (int)fx0;
        const int y0 = (int)fy0;

        const int base = (((x0 + PAD) * WP + (y0 + PAD)) << 8) + lane16;
        const char* p0 = volc + base;
        const uint4 q00 = *(const uint4*)(p0);                    // (x0,y0)
        const uint4 q01 = *(const uint4*)(p0 + 256);              // (x0,y1)
        const uint4 q10 = *(const uint4*)(p0 + ROW_BYTES);        // (x1,y0)
        const uint4 q11 = *(const uint4*)(p0 + ROW_BYTES + 256);  // (x1,y1)

        const float wx0 = 1.f - fx;
        const float wy0 = 1.f - fy;
        const __half2 w00 = __float2half2_rn(wx0 * wy0);  // (x0,y0)
        const __half2 w01 = __float2half2_rn(wx0 * fy);   // (x0,y1): y-frac
        const __half2 w10 = __float2half2_rn(fx  * wy0);  // (x1,y0): x-frac
        const __half2 w11 = __float2half2_rn(fx  * fy);   // (x1,y1)

        const __half2* h00 = (const __half2*)&q00;
        const __half2* h01 = (const __half2*)&q01;
        const __half2* h10 = (const __half2*)&q10;
        const __half2* h11 = (const __half2*)&q11;

#pragma unroll
        for (int j = 0; j < 4; ++j) {
            __half2 p = __hmul2(w00, h00[j]);
            p = __hfma2(w01, h01[j], p);
            p = __hfma2(w10, h10[j], p);
            p = __hfma2(w11, h11[j], p);
            const float2 f = __half22float2(p);
            accf[2 * j]     += f.x;
            accf[2 * j + 1] += f.y;
        }
    }

    float* op = dst + (size_t)blockIdx.z * SINO + ((size_t)u_i * A_N + a) * V_N + 8 * zo;
    *(float4*)(op)     = make_float4(accf[0] * scale, accf[1] * scale, accf[2] * scale, accf[3] * scale);
    *(float4*)(op + 4) = make_float4(accf[4] * scale, accf[5] * scale, accf[6] * scale, accf[7] * scale);
}

// ---- reduce: out = (p0+p1) * DT ----
__global__ __launch_bounds__(256) void reduce_segs2(
    const float4* __restrict__ p, float4* __restrict__ out)
{
    const size_t i = (size_t)blockIdx.x * 256 + threadIdx.x;  // SINO/4 threads
    const size_t q = SINO / 4;
    const float4 a = p[i];
    const float4 b = p[i + q];
    out[i] = make_float4((a.x + b.x) * DT, (a.y + b.y) * DT,
                         (a.z + b.z) * DT, (a.w + b.w) * DT);
}

// ---- fallback: fp32 volume, no workspace needed ----
__global__ __launch_bounds__(256) void joseph_fwd_f32(
    const float* __restrict__ vol,
    const float* __restrict__ angles,
    float* __restrict__ out)
{
    const int zo  = threadIdx.x & 15;
    const int r   = threadIdx.x >> 4;
    const int u_i = blockIdx.x * 16 + r;
    const int a   = blockIdx.y;

    const float ang = angles[a];
    const float c = cosf(ang);
    const float s = sinf(ang);
    const float u = (float)u_i - 63.5f;
    const float xb = fmaf(-u, s, 63.5f);
    const float yb = fmaf( u, c, 63.5f);

    const float* volz = vol + 8 * zo;
    float4 accA = make_float4(0.f, 0.f, 0.f, 0.f);
    float4 accB = make_float4(0.f, 0.f, 0.f, 0.f);

    for (int i = 0; i < NSTEPS; ++i) {
        const float t  = fmaf((float)i + 0.5f, DT, -T_HALF);
        const float xi = fmaf(t, c, xb);
        const float yi = fmaf(t, s, yb);
        const float fx0f = floorf(xi);
        const float fy0f = floorf(yi);
        const int x0 = (int)fx0f;
        const int y0 = (int)fy0f;
        const float fx = xi - fx0f;
        const float fy = yi - fy0f;
        const int x1 = x0 + 1;
        const int y1 = y0 + 1;
        const float wx0 = (x0 >= 0 && x0 < W_N) ? (1.f - fx) : 0.f;
        const float wx1 = (x1 >= 0 && x1 < W_N) ? fx : 0.f;
        const float wy0 = (y0 >= 0 && y0 < H_N) ? (1.f - fy) : 0.f;
        const float wy1 = (y1 >= 0 && y1 < H_N) ? fy : 0.f;
        if ((wx0 + wx1) == 0.f || (wy0 + wy1) == 0.f) continue;
        const int cx0 = min(max(x0, 0), W_N - 1);
        const int cx1 = min(max(x1, 0), W_N - 1);
        const int cy0 = min(max(y0, 0), H_N - 1);
        const int cy1 = min(max(y1, 0), H_N - 1);
        const float* p00 = volz + ((cx0 * H_N + cy0) << 7);
        const float* p01 = volz + ((cx1 * H_N + cy0) << 7);
        const float* p10 = volz + ((cx0 * H_N + cy1) << 7);
        const float* p11 = volz + ((cx1 * H_N + cy1) << 7);
        const float4 v00a = *(const float4*)(p00);
        const float4 v00b = *(const float4*)(p00 + 4);
        const float4 v01a = *(const float4*)(p01);
        const float4 v01b = *(const float4*)(p01 + 4);
        const float4 v10a = *(const float4*)(p10);
        const float4 v10b = *(const float4*)(p10 + 4);
        const float4 v11a = *(const float4*)(p11);
        const float4 v11b = *(const float4*)(p11 + 4);
        const float w00 = wx0 * wy0, w01 = wx1 * wy0, w10 = wx0 * wy1, w11 = wx1 * wy1;
        accA.x = fmaf(w00, v00a.x, fmaf(w01, v01a.x, fmaf(w10, v10a.x, fmaf(w11, v11a.x, accA.x))));
        accA.y = fmaf(w00, v00a.y, fmaf(w01, v01a.y, fmaf(w10, v10a.y, fmaf(w11, v11a.y, accA.y))));
        accA.z = fmaf(w00, v00a.z, fmaf(w01, v01a.z, fmaf(w10, v10a.z, fmaf(w11, v11a.z, accA.z))));
        accA.w = fmaf(w00, v00a.w, fmaf(w01, v01a.w, fmaf(w10, v10a.w, fmaf(w11, v11a.w, accA.w))));
        accB.x = fmaf(w00, v00b.x, fmaf(w01, v01b.x, fmaf(w10, v10b.x, fmaf(w11, v11b.x, accB.x))));
        accB.y = fmaf(w00, v00b.y, fmaf(w01, v01b.y, fmaf(w10, v10b.y, fmaf(w11, v11b.y, accB.y))));
        accB.z = fmaf(w00, v00b.z, fmaf(w01, v01b.z, fmaf(w10, v10b.z, fmaf(w11, v11b.z, accB.z))));
        accB.w = fmaf(w00, v00b.w, fmaf(w01, v01b.w, fmaf(w10, v10b.w, fmaf(w11, v11b.w, accB.w))));
    }

    float* op = out + ((size_t)u_i * A_N + a) * V_N + 8 * zo;
    *(float4*)(op)     = make_float4(accA.x * DT, accA.y * DT, accA.z * DT, accA.w * DT);
    *(float4*)(op + 4) = make_float4(accB.x * DT, accB.y * DT, accB.z * DT, accB.w * DT);
}

extern "C" void kernel_launch(void* const* d_in, const int* in_sizes, int n_in,
                              void* d_out, int out_size, void* d_ws, size_t ws_size,
                              hipStream_t stream) {
    const float* vol    = (const float*)d_in[0];
    const float* angles = (const float*)d_in[1];
    float* out          = (float*)d_out;

    const size_t need_full = VOLP_BYTES + SEGS * SINO * sizeof(float);
    const int pad_blocks = (int)((VOLP_COLS * 16 + 255) / 256);

    if (ws_size >= VOLP_BYTES) {
        unsigned int* volp = (unsigned int*)d_ws;
        hipLaunchKernelGGL(vol_pad_f16, dim3(pad_blocks), dim3(256), 0, stream, vol, volp);
        if (ws_size >= need_full) {
            float* partial = (float*)((char*)d_ws + VOLP_BYTES);
            dim3 grid(U_N / RAYS_PER_BLOCK, A_N, SEGS);   // 16 x 96 x 2 = 3072 blocks
            hipLaunchKernelGGL(joseph_fwd_inc, grid, dim3(BLOCK_THREADS), 0, stream,
                               (const unsigned short*)volp, angles, partial, 1.0f);
            hipLaunchKernelGGL(reduce_segs2, dim3(SINO / 4 / 256), dim3(256), 0, stream,
                               (const float4*)partial, (float4*)out);
        } else {
            dim3 grid(U_N / RAYS_PER_BLOCK, A_N, 1);
            hipLaunchKernelGGL(joseph_fwd_inc, grid, dim3(BLOCK_THREADS), 0, stream,
                               (const unsigned short*)volp, angles, out, DT);
        }
    } else {
        dim3 grid(U_N / 16, A_N);
        hipLaunchKernelGGL(joseph_fwd_f32, grid, dim3(256), 0, stream, vol, angles, out);
    }
}

// Round 12
// 112.165 us; speedup vs baseline: 1.0413x; 1.0331x over previous
//
#include <hip/hip_runtime.h>
#include <hip/hip_fp16.h>

namespace {
constexpr int A_N = 96;
constexpr int U_N = 128;
constexpr int V_N = 128;
constexpr int W_N = 128;
constexpr int H_N = 128;
constexpr int NSTEPS = 128;
constexpr float T_HALF = 89.80256121069154f;
constexpr float DT = 1.4031650189170554f;   // 2*T/NSTEPS
constexpr float INV_DT = 1.0f / DT;
constexpr int PAD = 6;                      // zero border: covers range slop + unroll alignment
constexpr int WP = W_N + 2 * PAD;           // 140 padded columns per row
constexpr int ROW_BYTES = WP * 256;         // x-stride in bytes (f16 column = 256 B)
constexpr int RAYS_PER_BLOCK = 8;           // 128-thread blocks
constexpr int BLOCK_THREADS = RAYS_PER_BLOCK * 16;
constexpr int SEGS = 2;
constexpr size_t VOLP_COLS = (size_t)WP * WP;          // 19600 columns
constexpr size_t VOLP_BYTES = VOLP_COLS * 256;         // ~5.02 MB
constexpr size_t SINO = (size_t)U_N * A_N * V_N;       // 1.57M floats
}

// ---- pack two floats -> half2 bits ----
__device__ __forceinline__ unsigned int packh2(float a, float b) {
    return (unsigned int)__half_as_ushort(__float2half_rn(a)) |
           ((unsigned int)__half_as_ushort(__float2half_rn(b)) << 16);
}

// ---- pre-pass: fp32 volume -> padded f16 volume (zero border of PAD cols) ----
__global__ __launch_bounds__(256) void vol_pad_f16(
    const float* __restrict__ vol, unsigned int* __restrict__ volp)
{
    const int idx = blockIdx.x * 256 + threadIdx.x;    // WP*WP*16 threads
    if (idx >= (int)(VOLP_COLS * 16)) return;
    const int zo  = idx & 15;
    const int col = idx >> 4;
    const int yp = col % WP;
    const int xp = col / WP;
    const int x = xp - PAD;
    const int y = yp - PAD;
    uint4 o = make_uint4(0u, 0u, 0u, 0u);
    if ((unsigned)x < 128u && (unsigned)y < 128u) {
        const float* src = vol + (((size_t)x * 128 + y) << 7) + zo * 8;
        const float4 f0 = *(const float4*)(src);
        const float4 f1 = *(const float4*)(src + 4);
        o.x = packh2(f0.x, f0.y);
        o.y = packh2(f0.z, f0.w);
        o.z = packh2(f1.x, f1.y);
        o.w = packh2(f1.z, f1.w);
    }
    *(uint4*)((char*)volp + (size_t)col * 256 + zo * 16) = o;
}

// ---- one bilinear step: returns base pointer for step i (no bounds checks) ----
__device__ __forceinline__ const char* step_base(
    const char* volc, int lane16, float i_f, float cv, float sv, float xb, float yb,
    float& fx, float& fy)
{
    const float tf = fmaf(i_f + 0.5f, DT, -T_HALF);
    const float xi = fmaf(tf, cv, xb);
    const float yi = fmaf(tf, sv, yb);
    const float fx0 = floorf(xi);
    const float fy0 = floorf(yi);
    fx = xi - fx0;
    fy = yi - fy0;
    const int x0 = (int)fx0;
    const int y0 = (int)fy0;
    const int base = (((x0 + PAD) * WP + (y0 + PAD)) << 8) + lane16;
    return volc + base;
}

__device__ __forceinline__ void consume(
    const uint4& q00, const uint4& q01, const uint4& q10, const uint4& q11,
    float fx, float fy, float* accf)
{
    const float wx0 = 1.f - fx;
    const float wy0 = 1.f - fy;
    const __half2 w00 = __float2half2_rn(wx0 * wy0);  // (x0,y0)
    const __half2 w01 = __float2half2_rn(wx0 * fy);   // (x0,y1)
    const __half2 w10 = __float2half2_rn(fx  * wy0);  // (x1,y0)
    const __half2 w11 = __float2half2_rn(fx  * fy);   // (x1,y1)
    const __half2* h00 = (const __half2*)&q00;
    const __half2* h01 = (const __half2*)&q01;
    const __half2* h10 = (const __half2*)&q10;
    const __half2* h11 = (const __half2*)&q11;
#pragma unroll
    for (int j = 0; j < 4; ++j) {
        __half2 p = __hmul2(w00, h00[j]);
        p = __hfma2(w01, h01[j], p);
        p = __hfma2(w10, h10[j], p);
        p = __hfma2(w11, h11[j], p);
        const float2 f = __half22float2(p);
        accf[2 * j]     += f.x;
        accf[2 * j + 1] += f.y;
    }
}

// ---- main projector: barrier-free, padded f16 volume, 2-step unrolled (8 loads in flight) ----
__global__ __launch_bounds__(BLOCK_THREADS) void joseph_fwd_inc(
    const unsigned short* __restrict__ volp,
    const float* __restrict__ angles,
    float* __restrict__ dst, float scale)
{
    const int zo  = threadIdx.x & 15;        // 16 z-groups of 8
    const int r   = threadIdx.x >> 4;        // ray in block
    const int u_i = blockIdx.x * RAYS_PER_BLOCK + r;
    const int a   = blockIdx.y;

    const int spseg = NSTEPS / gridDim.z;
    const int i0 = blockIdx.z * spseg;
    const int i1 = i0 + spseg;

    const float ang = angles[a];
    const float cv = cosf(ang);
    const float sv = sinf(ang);
    const float up = (float)u_i - 63.5f;
    const float xb = fmaf(-up, sv, 63.5f);
    const float yb = fmaf( up, cv, 63.5f);

    // valid-step range: xi,yi in (-1,128); +-2-step slop + 1 alignment step < PAD=6
    float tlo = -2.f * T_HALF, thi = 2.f * T_HALF;
    if (fabsf(cv) > 1e-6f) {
        const float ta = (-1.f - xb) / cv, tb = (128.f - xb) / cv;
        tlo = fmaxf(tlo, fminf(ta, tb));
        thi = fminf(thi, fmaxf(ta, tb));
    } else if (xb <= -1.f || xb >= 128.f) { thi = tlo - 1.f; }
    if (fabsf(sv) > 1e-6f) {
        const float ta = (-1.f - yb) / sv, tb = (128.f - yb) / sv;
        tlo = fmaxf(tlo, fminf(ta, tb));
        thi = fminf(thi, fmaxf(ta, tb));
    } else if (yb <= -1.f || yb >= 128.f) { thi = tlo - 1.f; }
    const int ilo = (int)floorf(fmaf(tlo + T_HALF, INV_DT, -0.5f)) - 1;
    const int ihi = (int)ceilf (fmaf(thi + T_HALF, INV_DT, -0.5f)) + 1;
    int lo = min(max(ilo, i0), i1);
    int hi = min(max(ihi + 1, i0), i1);
    lo &= ~1;                                  // even-align down (pad-safe)
    hi = (hi + 1) & ~1;                        // even-align up (pad-safe)
    if (hi > i1 + 0) hi = min(hi, ((i1 + 1) & ~1));  // stay within segment+1 parity
    // note: hi may exceed i1 by 1 only when i1 is odd (never: spseg even), so hi<=i1.

    const char* __restrict__ volc = (const char*)volp;
    const int lane16 = zo << 4;

    float accf[8];
#pragma unroll
    for (int k = 0; k < 8; ++k) accf[k] = 0.f;

    for (int i = lo; i < hi; i += 2) {
        float fxA, fyA, fxB, fyB;
        const char* pA = step_base(volc, lane16, (float)i,       cv, sv, xb, yb, fxA, fyA);
        const char* pB = step_base(volc, lane16, (float)(i + 1), cv, sv, xb, yb, fxB, fyB);

        // issue all 8 loads before consuming any
        const uint4 qA00 = *(const uint4*)(pA);
        const uint4 qA01 = *(const uint4*)(pA + 256);
        const uint4 qA10 = *(const uint4*)(pA + ROW_BYTES);
        const uint4 qA11 = *(const uint4*)(pA + ROW_BYTES + 256);
        const uint4 qB00 = *(const uint4*)(pB);
        const uint4 qB01 = *(const uint4*)(pB + 256);
        const uint4 qB10 = *(const uint4*)(pB + ROW_BYTES);
        const uint4 qB11 = *(const uint4*)(pB + ROW_BYTES + 256);

        consume(qA00, qA01, qA10, qA11, fxA, fyA, accf);
        consume(qB00, qB01, qB10, qB11, fxB, fyB, accf);
    }

    float* op = dst + (size_t)blockIdx.z * SINO + ((size_t)u_i * A_N + a) * V_N + 8 * zo;
    *(float4*)(op)     = make_float4(accf[0] * scale, accf[1] * scale, accf[2] * scale, accf[3] * scale);
    *(float4*)(op + 4) = make_float4(accf[4] * scale, accf[5] * scale, accf[6] * scale, accf[7] * scale);
}

// ---- reduce: out = (p0+p1) * DT ----
__global__ __launch_bounds__(256) void reduce_segs2(
    const float4* __restrict__ p, float4* __restrict__ out)
{
    const size_t i = (size_t)blockIdx.x * 256 + threadIdx.x;  // SINO/4 threads
    const size_t q = SINO / 4;
    const float4 a = p[i];
    const float4 b = p[i + q];
    out[i] = make_float4((a.x + b.x) * DT, (a.y + b.y) * DT,
                         (a.z + b.z) * DT, (a.w + b.w) * DT);
}

// ---- fallback: fp32 volume, no workspace needed ----
__global__ __launch_bounds__(256) void joseph_fwd_f32(
    const float* __restrict__ vol,
    const float* __restrict__ angles,
    float* __restrict__ out)
{
    const int zo  = threadIdx.x & 15;
    const int r   = threadIdx.x >> 4;
    const int u_i = blockIdx.x * 16 + r;
    const int a   = blockIdx.y;

    const float ang = angles[a];
    const float c = cosf(ang);
    const float s = sinf(ang);
    const float u = (float)u_i - 63.5f;
    const float xb = fmaf(-u, s, 63.5f);
    const float yb = fmaf( u, c, 63.5f);

    const float* volz = vol + 8 * zo;
    float4 accA = make_float4(0.f, 0.f, 0.f, 0.f);
    float4 accB = make_float4(0.f, 0.f, 0.f, 0.f);

    for (int i = 0; i < NSTEPS; ++i) {
        const float t  = fmaf((float)i + 0.5f, DT, -T_HALF);
        const float xi = fmaf(t, c, xb);
        const float yi = fmaf(t, s, yb);
        const float fx0f = floorf(xi);
        const float fy0f = floorf(yi);
        const int x0 = (int)fx0f;
        const int y0 = (int)fy0f;
        const float fx = xi - fx0f;
        const float fy = yi - fy0f;
        const int x1 = x0 + 1;
        const int y1 = y0 + 1;
        const float wx0 = (x0 >= 0 && x0 < W_N) ? (1.f - fx) : 0.f;
        const float wx1 = (x1 >= 0 && x1 < W_N) ? fx : 0.f;
        const float wy0 = (y0 >= 0 && y0 < H_N) ? (1.f - fy) : 0.f;
        const float wy1 = (y1 >= 0 && y1 < H_N) ? fy : 0.f;
        if ((wx0 + wx1) == 0.f || (wy0 + wy1) == 0.f) continue;
        const int cx0 = min(max(x0, 0), W_N - 1);
        const int cx1 = min(max(x1, 0), W_N - 1);
        const int cy0 = min(max(y0, 0), H_N - 1);
        const int cy1 = min(max(y1, 0), H_N - 1);
        const float* p00 = volz + ((cx0 * H_N + cy0) << 7);
        const float* p01 = volz + ((cx1 * H_N + cy0) << 7);
        const float* p10 = volz + ((cx0 * H_N + cy1) << 7);
        const float* p11 = volz + ((cx1 * H_N + cy1) << 7);
        const float4 v00a = *(const float4*)(p00);
        const float4 v00b = *(const float4*)(p00 + 4);
        const float4 v01a = *(const float4*)(p01);
        const float4 v01b = *(const float4*)(p01 + 4);
        const float4 v10a = *(const float4*)(p10);
        const float4 v10b = *(const float4*)(p10 + 4);
        const float4 v11a = *(const float4*)(p11);
        const float4 v11b = *(const float4*)(p11 + 4);
        const float w00 = wx0 * wy0, w01 = wx1 * wy0, w10 = wx0 * wy1, w11 = wx1 * wy1;
        accA.x = fmaf(w00, v00a.x, fmaf(w01, v01a.x, fmaf(w10, v10a.x, fmaf(w11, v11a.x, accA.x))));
        accA.y = fmaf(w00, v00a.y, fmaf(w01, v01a.y, fmaf(w10, v10a.y, fmaf(w11, v11a.y, accA.y))));
        accA.z = fmaf(w00, v00a.z, fmaf(w01, v01a.z, fmaf(w10, v10a.z, fmaf(w11, v11a.z, accA.z))));
        accA.w = fmaf(w00, v00a.w, fmaf(w01, v01a.w, fmaf(w10, v10a.w, fmaf(w11, v11a.w, accA.w))));
        accB.x = fmaf(w00, v00b.x, fmaf(w01, v01b.x, fmaf(w10, v10b.x, fmaf(w11, v11b.x, accB.x))));
        accB.y = fmaf(w00, v00b.y, fmaf(w01, v01b.y, fmaf(w10, v10b.y, fmaf(w11, v11b.y, accB.y))));
        accB.z = fmaf(w00, v00b.z, fmaf(w01, v01b.z, fmaf(w10, v10b.z, fmaf(w11, v11b.z, accB.z))));
        accB.w = fmaf(w00, v00b.w, fmaf(w01, v01b.w, fmaf(w10, v10b.w, fmaf(w11, v11b.w, accB.w))));
    }

    float* op = out + ((size_t)u_i * A_N + a) * V_N + 8 * zo;
    *(float4*)(op)     = make_float4(accA.x * DT, accA.y * DT, accA.z * DT, accA.w * DT);
    *(float4*)(op + 4) = make_float4(accB.x * DT, accB.y * DT, accB.z * DT, accB.w * DT);
}

extern "C" void kernel_launch(void* const* d_in, const int* in_sizes, int n_in,
                              void* d_out, int out_size, void* d_ws, size_t ws_size,
                              hipStream_t stream) {
    const float* vol    = (const float*)d_in[0];
    const float* angles = (const float*)d_in[1];
    float* out          = (float*)d_out;

    const size_t need_full = VOLP_BYTES + SEGS * SINO * sizeof(float);
    const int pad_blocks = (int)((VOLP_COLS * 16 + 255) / 256);

    if (ws_size >= VOLP_BYTES) {
        unsigned int* volp = (unsigned int*)d_ws;
        hipLaunchKernelGGL(vol_pad_f16, dim3(pad_blocks), dim3(256), 0, stream, vol, volp);
        if (ws_size >= need_full) {
            float* partial = (float*)((char*)d_ws + VOLP_BYTES);
            dim3 grid(U_N / RAYS_PER_BLOCK, A_N, SEGS);   // 16 x 96 x 2 = 3072 blocks
            hipLaunchKernelGGL(joseph_fwd_inc, grid, dim3(BLOCK_THREADS), 0, stream,
                               (const unsigned short*)volp, angles, partial, 1.0f);
            hipLaunchKernelGGL(reduce_segs2, dim3(SINO / 4 / 256), dim3(256), 0, stream,
                               (const float4*)partial, (float4*)out);
        } else {
            dim3 grid(U_N / RAYS_PER_BLOCK, A_N, 1);
            hipLaunchKernelGGL(joseph_fwd_inc, grid, dim3(BLOCK_THREADS), 0, stream,
                               (const unsigned short*)volp, angles, out, DT);
        }
    } else {
        dim3 grid(U_N / 16, A_N);
        hipLaunchKernelGGL(joseph_fwd_f32, grid, dim3(256), 0, stream, vol, angles, out);
    }
}